// Round 2
// baseline (2408.945 us; speedup 1.0000x reference)
//
#include <hip/hip_runtime.h>

// Monarch matrix: out = P(R_bdmm(P(L_bdmm(P(x))))) + bias, S=128, n=16384.
// Folded form:
//   Y[t][p][q]      = sum_k L[p,q,k] * x[t, k*128+p]          (stage A)
//   out[t,i*128+j]  = sum_m R[j,i,m] * Y[t][m][j] + bias[...] (stage B)
// Y layout: Y[t][p*128+q] (contiguous q within p-row).
// Y lives in d_ws (256 MB); fallback to in-place d_out with the validated
// round-1 kernels if ws_size is insufficient.

#define NFEAT 16384
#define SDIM  128

// Relaid weights: Lr[m][k][j] = L[m][j][k] ; Rr[j][m][i] = R[j][i][m].
__device__ float g_Lr[SDIM * SDIM * SDIM];
__device__ float g_Rr[SDIM * SDIM * SDIM];

__global__ __launch_bounds__(512, 2) void relayout_kernel(
    const float* __restrict__ L, const float* __restrict__ R) {
  unsigned idx = blockIdx.x * 512u + threadIdx.x;  // 0 .. 2^21-1
  unsigned a = idx >> 14;
  unsigned b = (idx >> 7) & 127u;
  unsigned c = idx & 127u;
  g_Lr[idx] = L[(a << 14) + (c << 7) + b];
  g_Rr[idx] = R[(a << 14) + (c << 7) + b];
}

// ================= New path: t-tile 32 for 4x weight reuse =================
// Stage A block: 32 t x 32 m (chunk mg) x 16 q (chunk jc).  512 threads.
// Thread FMA role: m_l = tid&31 (lane dim), jg = (tid>>5)&1, tq = tid>>6.
//   acc[4][8]: t = t0 + tq*4 + {0..3}, q = jc*16 + jg*8 + {0..7}.
// LDS x-tile per kc (8 k): xs[k 8][t 32][p pad 33]  (33.8 KB x 2 buffers).
//   reads lane-indexed by m_l -> conflict-free; writes <=2-way (free).
// XCD decode: bx&7 = mg + 4*(jc&1): per-XCD weight slice 1 MB (L2-resident),
//   x p-slice 64 MB (L3-local, shared by its 4 jc-blocks per t-tile).
__global__ __launch_bounds__(512, 4) void stageA32_kernel(
    const float* __restrict__ x, float* __restrict__ Y) {
  __shared__ float xs[2][8 * 32 * 33];

  const int tid = threadIdx.x;
  const int bx  = blockIdx.x;
  const int tt  = bx >> 5;
  const int c   = bx & 31;
  const int mg  = c & 3;         // m-chunk (32 wide)
  const int jc  = c >> 2;        // q-chunk (16 wide), 0..7
  const int t0  = tt << 5;
  const int p0  = mg << 5;

  const int m_l  = tid & 31;
  const int jg   = (tid >> 5) & 1;
  const int tq   = tid >> 6;
  const int j0   = (jc << 4) + (jg << 3);
  const int mcol = p0 + m_l;
  const int t4   = tq << 2;

  // staging role: sp = float4-within-128B-run, st = t, sq -> k = sq*4+i
  const int sp = tid & 7;
  const int st = (tid >> 3) & 31;
  const int sq = tid >> 8;

  float acc[4][8];
#pragma unroll
  for (int t = 0; t < 4; ++t)
#pragma unroll
    for (int j = 0; j < 8; ++j) acc[t][j] = 0.f;

  const float* wrow = g_Lr + ((size_t)mcol << 14) + j0;        // + k*128
  const float* xrow = x + (size_t)(t0 + st) * NFEAT + p0 + (sp << 2);

  // prologue: stage kc=0 into buf 0
  {
#pragma unroll
    for (int i = 0; i < 4; ++i) {
      const float4 v = *(const float4*)(xrow + (size_t)(((sq << 2) + i) << 7));
      float* d = &xs[0][((((sq << 2) + i) << 5) + st) * 33 + (sp << 2)];
      d[0] = v.x; d[1] = v.y; d[2] = v.z; d[3] = v.w;
    }
  }

  for (int kc = 0; kc < 16; ++kc) {
    __syncthreads();
    float4 pre[4];
    if (kc < 15) {
#pragma unroll
      for (int i = 0; i < 4; ++i)
        pre[i] = *(const float4*)(xrow +
                 (size_t)((((kc + 1) << 3) + (sq << 2) + i) << 7));
    }
    const float* xb = xs[kc & 1];
#pragma unroll
    for (int kk = 0; kk < 8; ++kk) {
      const size_t k = (size_t)((kc << 3) + kk);
      const float4 wa = *(const float4*)(wrow + (k << 7));
      const float4 wb = *(const float4*)(wrow + (k << 7) + 4);
      const float xv0 = xb[((kk << 5) + t4 + 0) * 33 + m_l];
      const float xv1 = xb[((kk << 5) + t4 + 1) * 33 + m_l];
      const float xv2 = xb[((kk << 5) + t4 + 2) * 33 + m_l];
      const float xv3 = xb[((kk << 5) + t4 + 3) * 33 + m_l];
      const float wv[8] = {wa.x, wa.y, wa.z, wa.w, wb.x, wb.y, wb.z, wb.w};
      const float xv[4] = {xv0, xv1, xv2, xv3};
#pragma unroll
      for (int t = 0; t < 4; ++t)
#pragma unroll
        for (int j = 0; j < 8; ++j) acc[t][j] = fmaf(xv[t], wv[j], acc[t][j]);
    }
    if (kc < 15) {
      float* xn = xs[(kc + 1) & 1];
#pragma unroll
      for (int i = 0; i < 4; ++i) {
        float* d = &xn[((((sq << 2) + i) << 5) + st) * 33 + (sp << 2)];
        d[0] = pre[i].x; d[1] = pre[i].y; d[2] = pre[i].z; d[3] = pre[i].w;
      }
    }
  }

  // Y[t][mcol*128 + j0 .. +7]: 32B chunks; jg pair completes 64B sectors.
#pragma unroll
  for (int t = 0; t < 4; ++t) {
    float* p = Y + (size_t)(t0 + t4 + t) * NFEAT + (mcol << 7) + j0;
    float4 o0 = {acc[t][0], acc[t][1], acc[t][2], acc[t][3]};
    float4 o1 = {acc[t][4], acc[t][5], acc[t][6], acc[t][7]};
    *(float4*)p = o0;
    *(float4*)(p + 4) = o1;
  }
}

// Stage B block: 32 t x 32 j (chunk jc2) x 16 i (chunk ic).  512 threads.
// acc[4][8]: t = t0+tq*4+{0..3}, i = ic*16 + ig*8 + {0..7}; lane dim j.
// XCD decode: bx&7 = jc2 + 4*(ic&1): per-XCD R slice 1 MB, Y j-slice 64 MB.
__global__ __launch_bounds__(512, 4) void stageB32_kernel(
    const float* __restrict__ Y, const float* __restrict__ bias,
    float* __restrict__ out) {
  __shared__ float ys[2][8 * 32 * 33];

  const int tid = threadIdx.x;
  const int bx  = blockIdx.x;
  const int tt  = bx >> 5;
  const int c   = bx & 31;
  const int jc2 = c & 3;         // j-chunk (32 wide)
  const int ic  = c >> 2;        // i-chunk (16 wide), 0..7
  const int t0  = tt << 5;
  const int jb  = jc2 << 5;

  const int j_l  = tid & 31;
  const int ig   = (tid >> 5) & 1;
  const int tq   = tid >> 6;
  const int i0   = (ic << 4) + (ig << 3);
  const int jcol = jb + j_l;
  const int t4   = tq << 2;

  const int sp = tid & 7;
  const int st = (tid >> 3) & 31;
  const int sq = tid >> 8;

  float acc[4][8];
#pragma unroll
  for (int t = 0; t < 4; ++t)
#pragma unroll
    for (int i = 0; i < 8; ++i) acc[t][i] = 0.f;

  const float* wrow = g_Rr + ((size_t)jcol << 14) + i0;        // + m*128
  const float* yrow = Y + (size_t)(t0 + st) * NFEAT + jb + (sp << 2);

  {
#pragma unroll
    for (int i = 0; i < 4; ++i) {
      const float4 v = *(const float4*)(yrow + (size_t)(((sq << 2) + i) << 7));
      float* d = &ys[0][((((sq << 2) + i) << 5) + st) * 33 + (sp << 2)];
      d[0] = v.x; d[1] = v.y; d[2] = v.z; d[3] = v.w;
    }
  }

  for (int mc = 0; mc < 16; ++mc) {
    __syncthreads();
    float4 pre[4];
    if (mc < 15) {
#pragma unroll
      for (int i = 0; i < 4; ++i)
        pre[i] = *(const float4*)(yrow +
                 (size_t)((((mc + 1) << 3) + (sq << 2) + i) << 7));
    }
    const float* yb = ys[mc & 1];
#pragma unroll
    for (int mm = 0; mm < 8; ++mm) {
      const size_t m = (size_t)((mc << 3) + mm);
      const float4 wa = *(const float4*)(wrow + (m << 7));
      const float4 wb = *(const float4*)(wrow + (m << 7) + 4);
      const float yv0 = yb[((mm << 5) + t4 + 0) * 33 + j_l];
      const float yv1 = yb[((mm << 5) + t4 + 1) * 33 + j_l];
      const float yv2 = yb[((mm << 5) + t4 + 2) * 33 + j_l];
      const float yv3 = yb[((mm << 5) + t4 + 3) * 33 + j_l];
      const float wv[8] = {wa.x, wa.y, wa.z, wa.w, wb.x, wb.y, wb.z, wb.w};
      const float yv[4] = {yv0, yv1, yv2, yv3};
#pragma unroll
      for (int t = 0; t < 4; ++t)
#pragma unroll
        for (int i = 0; i < 8; ++i) acc[t][i] = fmaf(yv[t], wv[i], acc[t][i]);
    }
    if (mc < 15) {
      float* yn = ys[(mc + 1) & 1];
#pragma unroll
      for (int i = 0; i < 4; ++i) {
        float* d = &yn[((((sq << 2) + i) << 5) + st) * 33 + (sp << 2)];
        d[0] = pre[i].x; d[1] = pre[i].y; d[2] = pre[i].z; d[3] = pre[i].w;
      }
    }
  }

  float bv[8];
#pragma unroll
  for (int ii = 0; ii < 8; ++ii) bv[ii] = bias[((i0 + ii) << 7) + jcol];
#pragma unroll
  for (int t = 0; t < 4; ++t)
#pragma unroll
    for (int ii = 0; ii < 8; ++ii)
      out[(size_t)(t0 + t4 + t) * NFEAT + ((i0 + ii) << 7) + jcol] =
          acc[t][ii] + bv[ii];
}

// ================= Fallback path (round-1, validated, in-place) ============
__global__ __launch_bounds__(512, 4) void stageA8_kernel(
    const float* __restrict__ x, float* __restrict__ Y) {
  __shared__ float xs[2][8 * 32 * 12];
  const int tid = threadIdx.x;
  const int bx  = blockIdx.x;
  const int xcd = bx & 7;
  const int mc  = xcd & 3;
  const int tt  = ((bx >> 3) << 1) | (xcd >> 2);
  const int t0  = tt << 3;
  const int m_l  = tid >> 4;
  const int mcol = (mc << 5) + m_l;
  const int j0   = (tid & 15) << 3;
  const int s_m  = tid & 31;
  const int s_k  = (tid >> 5) & 7;
  const int s_th = tid >> 8;
  float acc[8][8];
#pragma unroll
  for (int t = 0; t < 8; ++t)
#pragma unroll
    for (int j = 0; j < 8; ++j) acc[t][j] = 0.f;
  const float* xsrc = x + (size_t)(t0 + (s_th << 2)) * NFEAT + (mc << 5) + s_m;
  const float* wrow = g_Lr + ((size_t)mcol << 14) + j0;
  const int sidx = ((s_k << 5) + s_m) * 12 + (s_th << 2);
  {
    const float* s = xsrc + (size_t)s_k * SDIM;
    float4 v; v.x = s[0]; v.y = s[NFEAT]; v.z = s[2 * NFEAT]; v.w = s[3 * NFEAT];
    *(float4*)&xs[0][sidx] = v;
  }
  for (int kc = 0; kc < 16; ++kc) {
    __syncthreads();
    float4 vn;
    if (kc < 15) {
      const float* s = xsrc + (size_t)(((kc + 1) << 3) + s_k) * SDIM;
      vn.x = s[0]; vn.y = s[NFEAT]; vn.z = s[2 * NFEAT]; vn.w = s[3 * NFEAT];
    }
    const float* xb = &xs[kc & 1][0];
#pragma unroll
    for (int kk = 0; kk < 8; ++kk) {
      const int k = (kc << 3) + kk;
      const float4 xa = *(const float4*)&xb[((kk << 5) + m_l) * 12 + 0];
      const float4 xc = *(const float4*)&xb[((kk << 5) + m_l) * 12 + 4];
      const float4 wa = *(const float4*)&wrow[(size_t)k << 7];
      const float4 wb = *(const float4*)&wrow[((size_t)k << 7) + 4];
      const float xv[8] = {xa.x, xa.y, xa.z, xa.w, xc.x, xc.y, xc.z, xc.w};
      const float wv[8] = {wa.x, wa.y, wa.z, wa.w, wb.x, wb.y, wb.z, wb.w};
#pragma unroll
      for (int t = 0; t < 8; ++t)
#pragma unroll
        for (int j = 0; j < 8; ++j) acc[t][j] = fmaf(xv[t], wv[j], acc[t][j]);
    }
    if (kc < 15) *(float4*)&xs[(kc + 1) & 1][sidx] = vn;
  }
  float* yrow = Y + ((size_t)mcol << 7) + j0;
#pragma unroll
  for (int t = 0; t < 8; ++t) {
    float4 o0 = {acc[t][0], acc[t][1], acc[t][2], acc[t][3]};
    float4 o1 = {acc[t][4], acc[t][5], acc[t][6], acc[t][7]};
    float* p = yrow + (size_t)(t0 + t) * NFEAT;
    *(float4*)p = o0; *(float4*)(p + 4) = o1;
  }
}

__global__ __launch_bounds__(512, 4) void stageB8_kernel(
    const float* __restrict__ bias, float* buf) {
  __shared__ float ys[2][8 * 32 * 12];
  const int tid = threadIdx.x;
  const int bx  = blockIdx.x;
  const int xcd = bx & 7;
  const int jc  = xcd & 3;
  const int tt  = ((bx >> 3) << 1) | (xcd >> 2);
  const int t0  = tt << 3;
  const int jl   = tid & 31;
  const int jcol = (jc << 5) + jl;
  const int i0   = (tid >> 5) << 3;
  const int s_j  = tid & 31;
  const int s_mu = (tid >> 5) & 7;
  const int s_th = tid >> 8;
  float acc[8][8];
#pragma unroll
  for (int t = 0; t < 8; ++t)
#pragma unroll
    for (int i = 0; i < 8; ++i) acc[t][i] = 0.f;
  const float* ysrc = buf + (size_t)(t0 + (s_th << 2)) * NFEAT + (jc << 5) + s_j;
  const float* wrow = g_Rr + ((size_t)jcol << 14) + i0;
  const int sidx = ((s_mu << 5) + s_j) * 12 + (s_th << 2);
  {
    const float* s = ysrc + (size_t)s_mu * SDIM;
    float4 v; v.x = s[0]; v.y = s[NFEAT]; v.z = s[2 * NFEAT]; v.w = s[3 * NFEAT];
    *(float4*)&ys[0][sidx] = v;
  }
  for (int mcc = 0; mcc < 16; ++mcc) {
    __syncthreads();
    float4 vn;
    if (mcc < 15) {
      const float* s = ysrc + (size_t)(((mcc + 1) << 3) + s_mu) * SDIM;
      vn.x = s[0]; vn.y = s[NFEAT]; vn.z = s[2 * NFEAT]; vn.w = s[3 * NFEAT];
    }
    const float* yb = &ys[mcc & 1][0];
#pragma unroll
    for (int mm = 0; mm < 8; ++mm) {
      const int m = (mcc << 3) + mm;
      const float4 ya = *(const float4*)&yb[((mm << 5) + jl) * 12 + 0];
      const float4 yc = *(const float4*)&yb[((mm << 5) + jl) * 12 + 4];
      const float4 wa = *(const float4*)&wrow[(size_t)m << 7];
      const float4 wb = *(const float4*)&wrow[((size_t)m << 7) + 4];
      const float yv[8] = {ya.x, ya.y, ya.z, ya.w, yc.x, yc.y, yc.z, yc.w};
      const float wv[8] = {wa.x, wa.y, wa.z, wa.w, wb.x, wb.y, wb.z, wb.w};
#pragma unroll
      for (int t = 0; t < 8; ++t)
#pragma unroll
        for (int i = 0; i < 8; ++i) acc[t][i] = fmaf(yv[t], wv[i], acc[t][i]);
    }
    if (mcc < 15) *(float4*)&ys[(mcc + 1) & 1][sidx] = vn;
  }
#pragma unroll
  for (int ii = 0; ii < 8; ++ii) {
    const float b = bias[((i0 + ii) << 7) + jcol];
#pragma unroll
    for (int t = 0; t < 8; ++t)
      buf[(size_t)(t0 + t) * NFEAT + ((i0 + ii) << 7) + jcol] = acc[t][ii] + b;
  }
}

extern "C" void kernel_launch(void* const* d_in, const int* in_sizes, int n_in,
                              void* d_out, int out_size, void* d_ws, size_t ws_size,
                              hipStream_t stream) {
  const float* x    = (const float*)d_in[0];
  const float* L    = (const float*)d_in[1];
  const float* R    = (const float*)d_in[2];
  const float* bias = (const float*)d_in[3];
  float* out = (float*)d_out;

  const int rows = in_sizes[0] / NFEAT;   // 4096
  const size_t y_bytes = (size_t)rows * NFEAT * sizeof(float);

  relayout_kernel<<<(SDIM * SDIM * SDIM) / 512, 512, 0, stream>>>(L, R);

  if ((rows % 32) == 0 && ws_size >= y_bytes) {
    float* Ybuf = (float*)d_ws;
    const int nblk = (rows / 32) * 32;  // 4096
    stageA32_kernel<<<nblk, 512, 0, stream>>>(x, Ybuf);
    stageB32_kernel<<<nblk, 512, 0, stream>>>(Ybuf, bias, out);
  } else {
    const int nblk = (rows / 8) * 4;    // in-place fallback (round-1 path)
    stageA8_kernel<<<nblk, 512, 0, stream>>>(x, out);
    stageB8_kernel<<<nblk, 512, 0, stream>>>(bias, out);
  }
}